// Round 1
// 437.363 us; speedup vs baseline: 1.0764x; 1.0764x over previous
//
#include <hip/hip_runtime.h>
#include <hip/hip_bf16.h>

// BronxLayer fused implementation for MI355X (gfx950).  Round 6.
// r5 was 470us with k3_fused at 230us, stall-bound: MfmaUtil 5%, VALUBusy 26%,
// HBM 8.6%, occupancy 17%.  Root cause: wave=head decomposition forced
// cross-wave eps staging -> 2 barriers x 24 iters with vmcnt(0) drains at
// 3 blocks/CU (64-AGPR acc capped occupancy).
//
// Round-6 restructure: split k3 into two single-regime kernels.
//  - k3a_elem: wave owns a 64-z stripe for ALL 4 heads.  eps f32x4 at (x,z)
//    = 4 heads lands exactly in the MFMA S^T output lane layout -> no LDS,
//    NO barriers, pure streaming (189 MB in, 75 MB bf16 "a" out).  Computes
//    S_mu/S_ls (8 MFMA/subtile), softplus/exp/KL, den, writes a[b][x][z].
//  - k3b_agg: out[x,b,h] = sum_z a_b[x,z] hn[z,h] as a standard bf16 GEMM
//    (BM=64, BN=256 full, BK=64, K-split 2 -> 384 blocks all co-resident at
//    2 blocks/CU).  global_load_lds staging with XOR-swizzled LDS
//    (swizzle applied to BOTH source addr and ds_read addr - involution).
//  - k35 reduce shrinks 200 MB -> 25 MB (split 4 -> 2), normalizes -> bf16.

#define NN 3072
#define HH 256
#define NB 4
#define HD 64
constexpr int KS = 2;                    // k-splits for agg GEMM
constexpr int CZ = 256;                  // z per k3a block
constexpr int NCH = NN / CZ;             // 12 chunks
constexpr int KMLSZ = 192 * 2 * 64 * 8;  // shorts per (mat,head)

typedef __attribute__((ext_vector_type(8))) short bf16x8;
typedef __attribute__((ext_vector_type(4))) float f32x4;

static __device__ inline short f2bf(float f) {
    __hip_bfloat16 h = __float2bfloat16(f);
    return __builtin_bit_cast(short, h);
}

typedef const __attribute__((address_space(1))) unsigned int* gas_ptr;
typedef __attribute__((address_space(3))) unsigned int* las_ptr;
static __device__ inline void gload_lds16(const void* g, void* l) {
    __builtin_amdgcn_global_load_lds((gas_ptr)g, (las_ptr)l, 16, 0, 0);
}

// ---------------- k0: weight prep + zero denom/klsum ----------------
__global__ void k0_prep(const float* __restrict__ Wk, const float* __restrict__ Wmu,
                        const float* __restrict__ Wls, const float* __restrict__ bk,
                        const float* __restrict__ bmu, const float* __restrict__ bls,
                        const float* __restrict__ Wv, short* __restrict__ WTcat,
                        float* __restrict__ biascat, short* __restrict__ WvT,
                        float* __restrict__ denom) {
    __shared__ float t[64][65];
    int bx = blockIdx.x;
    if (bx < 48) {
        int mat = bx >> 4;
        int by = (bx >> 2) & 3, bc = bx & 3;
        int y0 = by * 64, c0 = bc * 64;
        const float* W = (mat == 0) ? Wk : (mat == 1 ? Wmu : Wls);
        float scale = (mat == 0) ? 0.125f : 1.f;
        int r = threadIdx.x >> 4, c4 = (threadIdx.x & 15) * 4;
#pragma unroll
        for (int i = 0; i < 4; i++) {
            int yl = r + i * 16;
            float4 v = *(const float4*)(W + (y0 + yl) * 256 + c0 + c4);
            t[yl][c4] = v.x; t[yl][c4 + 1] = v.y; t[yl][c4 + 2] = v.z; t[yl][c4 + 3] = v.w;
        }
        __syncthreads();
#pragma unroll
        for (int i = 0; i < 4; i++) {
            int cl = r + i * 16;
            int corig = c0 + cl;
            int cp = mat * 256 + (corig & 3) * 64 + (corig >> 2);
            short4 v = make_short4(f2bf(t[c4][cl] * scale), f2bf(t[c4 + 1][cl] * scale),
                                   f2bf(t[c4 + 2][cl] * scale), f2bf(t[c4 + 3][cl] * scale));
            *(short4*)(WTcat + cp * 256 + y0 + c4) = v;
        }
        return;
    }
    if (bx < 112) {
        int b = bx - 48;
        int bk2 = b >> 2, bn = b & 3;
        int k0 = bk2 * 64, n0 = bn * 64;
        int r = threadIdx.x >> 4, c4 = (threadIdx.x & 15) * 4;
#pragma unroll
        for (int i = 0; i < 4; i++) {
            int kk = r + i * 16;
            float4 v = *(const float4*)(Wv + (k0 + kk) * 256 + n0 + c4);
            t[kk][c4] = v.x; t[kk][c4 + 1] = v.y; t[kk][c4 + 2] = v.z; t[kk][c4 + 3] = v.w;
        }
        __syncthreads();
#pragma unroll
        for (int i = 0; i < 4; i++) {
            int nn = r + i * 16;
            short4 v = make_short4(f2bf(t[c4][nn]), f2bf(t[c4 + 1][nn]),
                                   f2bf(t[c4 + 2][nn]), f2bf(t[c4 + 3][nn]));
            *(short4*)(WvT + (n0 + nn) * 1024 + k0 + c4) = v;
        }
        return;
    }
    if (bx == 112) {
        int cc = threadIdx.x;
        int corig = (cc & 63) * 4 + (cc >> 6);
        biascat[cc] = bk[corig] * 0.125f;
        biascat[256 + cc] = bmu[corig];
        biascat[512 + cc] = bls[corig];
        return;
    }
    int i = (bx - 113) * 256 + threadIdx.x;
    if (i < 13312) denom[i] = 0.f;   // denom[12288] then klsum[1024], contiguous
}

// ---------------- k1: LayerNorm ----------------
__global__ void k1_ln(const float* __restrict__ h, const float* __restrict__ gamma,
                      const float* __restrict__ beta, short* __restrict__ hn) {
    int row = blockIdx.x, tid = threadIdx.x;
    float v = h[row * 256 + tid];
    float s = v, s2 = v * v;
    for (int off = 32; off; off >>= 1) {
        s += __shfl_xor(s, off);
        s2 += __shfl_xor(s2, off);
    }
    __shared__ float red[8];
    int w = tid >> 6, lane = tid & 63;
    if (!lane) { red[w] = s; red[4 + w] = s2; }
    __syncthreads();
    s = red[0] + red[1] + red[2] + red[3];
    s2 = red[4] + red[5] + red[6] + red[7];
    float mean = s * (1.f / 256.f);
    float var = s2 * (1.f / 256.f) - mean * mean;
    float rs = rsqrtf(var + 1e-5f);
    hn[row * 256 + tid] = f2bf((v - mean) * rs * gamma[tid] + beta[tid]);
}

// ---------------- k1b: transpose hn -> hnT (LDS-tiled) ----------------
__global__ void k1b_tr(const short* __restrict__ hn, short* __restrict__ hnT) {
    __shared__ short t[64][68];
    int bn = blockIdx.x >> 2, bh = blockIdx.x & 3;
    int n0 = bn * 64, h0 = bh * 64;
    int r = threadIdx.x >> 4, c4 = (threadIdx.x & 15) * 4;
#pragma unroll
    for (int i = 0; i < 4; i++) {
        int nn = r + i * 16;
        *(short4*)&t[nn][c4] = *(const short4*)(hn + (n0 + nn) * 256 + h0 + c4);
    }
    __syncthreads();
#pragma unroll
    for (int i = 0; i < 4; i++) {
        int hh = r + i * 16;
        short4 v = make_short4(t[c4][hh], t[c4 + 1][hh], t[c4 + 2][hh], t[c4 + 3][hh]);
        *(short4*)(hnT + (h0 + hh) * NN + n0 + c4) = v;
    }
}

// ---------------- k2: projections (bf16 MFMA), fragment-packed output -----------
// kml packed per (mat,head): idx = ((zt*2 + khalf)*64 + lane)*8 + j
//   element: node z = zt*16 + (lane&15), k = khalf*32 + (lane>>4)*8 + j
__global__ __launch_bounds__(256) void k2_proj(const short* __restrict__ hn,
                                               const short* __restrict__ WTcat,
                                               const float* __restrict__ biascat,
                                               short* __restrict__ kml) {
    int bx = blockIdx.x;
    int mt = bx / 12, nb = bx % 12;
    int m0 = mt * 64, n0 = nb * 64;
    int tid = threadIdx.x, w = tid >> 6, lane = tid & 63, q = lane >> 4, c = lane & 15;
    int mrow = m0 + w * 16;
    f32x4 acc[4] = {{0, 0, 0, 0}, {0, 0, 0, 0}, {0, 0, 0, 0}, {0, 0, 0, 0}};
    for (int k0 = 0; k0 < 256; k0 += 32) {
        bf16x8 af = *(const bf16x8*)(hn + (mrow + c) * 256 + k0 + q * 8);
#pragma unroll
        for (int nt = 0; nt < 4; nt++) {
            bf16x8 bf = *(const bf16x8*)(WTcat + (n0 + nt * 16 + c) * 256 + k0 + q * 8);
            acc[nt] = __builtin_amdgcn_mfma_f32_16x16x32_bf16(af, bf, acc[nt], 0, 0, 0);
        }
    }
#pragma unroll
    for (int nt = 0; nt < 4; nt++) {
        int cp = n0 + nt * 16 + c;
        float bias = biascat[cp];
        int mat = cp >> 8, b = (cp >> 6) & 3, y = cp & 63;
        short* dst = kml + (size_t)(mat * 4 + b) * KMLSZ;
        int kh2 = y >> 5, lq = (y >> 3) & 3, j = y & 7;
        int zt = mt * 4 + w;  // m>>4
#pragma unroll
        for (int r = 0; r < 4; r++) {
            int ml = 4 * q + r;  // m&15
            dst[(((zt * 2 + kh2) * 64) + lq * 16 + ml) * 8 + j] = f2bf(acc[nt][r] + bias);
        }
    }
}

// ---------------- k3a: elementwise core (barrier-free streaming) ----------------
// Block: 16 x-rows (xt) x CZ z (chunk).  Wave w owns z-stripe [w*64, w*64+64)
// for ALL 4 heads.  S^T MFMA layout: lane(q,c) -> x = x0+c, z = zt*16+4q+r, so
// eps[x][z][0..3] is a single per-lane f32x4 load.  No LDS staging, no barriers.
__global__ __launch_bounds__(256) void k3a_elem(
    const short* __restrict__ kml, const float* __restrict__ eps,
    const float* __restrict__ diff, short* __restrict__ a,
    float* __restrict__ denom, float* __restrict__ klsum) {
    __shared__ float klred[4];
    const int tid = threadIdx.x;
    const int w = tid >> 6, lane = tid & 63, q = lane >> 4, c = lane & 15;
    const int xt = blockIdx.x % 192;
    const int ch = blockIdx.x / 192;
    const int x0 = xt * 16;
    const int zw = ch * CZ + w * 64;     // this wave's 64-z stripe

    // kh fragments (B-operand of S^T), one per (head, k-half), hoisted
    bf16x8 qf[NB][2];
#pragma unroll
    for (int b = 0; b < NB; b++)
#pragma unroll
        for (int kh = 0; kh < 2; kh++)
            qf[b][kh] = *(const bf16x8*)(kml + (size_t)b * KMLSZ +
                                         ((xt * 2 + kh) * 64 + lane) * 8);

    float den_acc[NB] = {0.f, 0.f, 0.f, 0.f};
    float kl_acc = 0.f;
    const size_t xrow = (size_t)(x0 + c) * NN;

#pragma unroll
    for (int t = 0; t < 4; t++) {
        const int z = zw + t * 16;
        const int zt2 = z >> 4;
        // eps gathers: f32x4 = all 4 heads at (x,z); the 4 r-loads of a lane
        // share one 64B line group -> L1 reuse.  diff: one line per x-row.
        f32x4 e4[4];
        float dif[4];
#pragma unroll
        for (int r = 0; r < 4; r++) {
            e4[r] = *(const f32x4*)(eps + (xrow + (size_t)(z + 4 * q + r)) * 4);
            dif[r] = diff[xrow + z + 4 * q + r];
        }
#pragma unroll
        for (int b = 0; b < NB; b++) {
            const short* mup = kml + (size_t)(NB + b) * KMLSZ;
            const short* lsp = kml + (size_t)(2 * NB + b) * KMLSZ;
            bf16x8 a0 = *(const bf16x8*)(mup + ((zt2 * 2 + 0) * 64 + lane) * 8);
            bf16x8 a1 = *(const bf16x8*)(mup + ((zt2 * 2 + 1) * 64 + lane) * 8);
            f32x4 smu = {0.f, 0.f, 0.f, 0.f};
            smu = __builtin_amdgcn_mfma_f32_16x16x32_bf16(a0, qf[b][0], smu, 0, 0, 0);
            smu = __builtin_amdgcn_mfma_f32_16x16x32_bf16(a1, qf[b][1], smu, 0, 0, 0);
            bf16x8 l0 = *(const bf16x8*)(lsp + ((zt2 * 2 + 0) * 64 + lane) * 8);
            bf16x8 l1 = *(const bf16x8*)(lsp + ((zt2 * 2 + 1) * 64 + lane) * 8);
            f32x4 sls = {0.f, 0.f, 0.f, 0.f};
            sls = __builtin_amdgcn_mfma_f32_16x16x32_bf16(l0, qf[b][0], sls, 0, 0, 0);
            sls = __builtin_amdgcn_mfma_f32_16x16x32_bf16(l1, qf[b][1], sls, 0, 0, 0);
            short pk[4];
#pragma unroll
            for (int r = 0; r < 4; r++) {
                float mu = smu[r];
                float ls = sls[r];
                float e = e4[r][b];
                float d = dif[r];
                float ex = __expf(-fabsf(ls));
                float sg = fmaxf(ls, 0.f) + __logf(1.f + ex);
                float kle = -__logf(sg) + 0.5f * (sg * sg + mu * mu) - 0.5f;
                float sgn = (d > 0.f) ? 1.f : ((d < 0.f) ? -1.f : 0.f);
                kl_acc += sgn * kle;
                float av = __expf(mu + sg * e) * d;
                den_acc[b] += fabsf(av);
                pk[r] = f2bf(av);
            }
            *(short4*)(a + ((size_t)b * NN + x0 + c) * NN + z + 4 * q) =
                make_short4(pk[0], pk[1], pk[2], pk[3]);
        }
    }
    // denominator: lane's elements all at x = x0 + c; reduce across quads
#pragma unroll
    for (int b = 0; b < NB; b++) {
        float d = den_acc[b];
        d += __shfl_down(d, 32);
        d += __shfl_down(d, 16);
        if (q == 0) atomicAdd(&denom[(x0 + c) * NB + b], d);
    }
    for (int off = 32; off; off >>= 1) kl_acc += __shfl_xor(kl_acc, off);
    if (lane == 0) klred[w] = kl_acc;
    __syncthreads();
    if (tid == 0) atomicAdd(klsum, klred[0] + klred[1] + klred[2] + klred[3]);
}

// ---------------- k3b: aggregation GEMM (per head) ----------------
// out_p[x, b*256+h] = sum_z a[b][x][z] * hnT[h][z].  BM=64, BN=256 (full),
// BK=64, K-split 2.  384 blocks, 80 KB LDS -> 2 blocks/CU, all co-resident.
// LDS XOR-swizzle (row&7)<<4 applied to BOTH the global source byte-offset
// (global_load_lds writes linearly) and the ds_read address (involution).
__global__ __launch_bounds__(256) void k3b_agg(
    const short* __restrict__ a, const short* __restrict__ hnT,
    float* __restrict__ aggp) {
    __shared__ short As[2][64 * 64];
    __shared__ short Bs[2][256 * 64];
    const int tid = threadIdx.x;
    const int w = tid >> 6, lane = tid & 63, q = lane >> 4, c = lane & 15;
    const int bid = blockIdx.x;
    const int b = bid & 3;
    const int ksp = (bid >> 2) & 1;
    const int m0 = (bid >> 3) * 64;
    const int kbase = ksp * (NN / KS);   // 1536

    const char* Ag = (const char*)(a + ((size_t)b * NN + m0) * NN + kbase);
    const char* Bg = (const char*)(hnT + kbase);

    f32x4 acc[4][4];
#pragma unroll
    for (int i = 0; i < 4; i++)
#pragma unroll
        for (int j = 0; j < 4; j++) acc[i][j] = (f32x4){0.f, 0.f, 0.f, 0.f};

    auto stage = [&](int buf, int ks) {
        const int kb = ks * 128;  // byte offset along k (64 bf16)
#pragma unroll
        for (int l = 0; l < 2; l++) {   // A: 8 KB
            int idx = l * 256 + tid;
            int row = idx >> 3;
            int colb = ((idx & 7) * 16) ^ ((row & 7) << 4);
            gload_lds16(Ag + (size_t)row * (NN * 2) + kb + colb,
                        (char*)&As[buf][0] + idx * 16);
        }
#pragma unroll
        for (int l = 0; l < 8; l++) {   // B: 32 KB
            int idx = l * 256 + tid;
            int row = idx >> 3;
            int colb = ((idx & 7) * 16) ^ ((row & 7) << 4);
            gload_lds16(Bg + (size_t)row * (NN * 2) + kb + colb,
                        (char*)&Bs[buf][0] + idx * 16);
        }
    };

    stage(0, 0);
    int cur = 0;
    for (int ks = 0; ks < NN / KS / 64; ks++) {
        __syncthreads();   // drains vmcnt(0): buf[cur] staged & visible
        if (ks + 1 < NN / KS / 64) stage(cur ^ 1, ks + 1);
        bf16x8 af[4][2], bf[4][2];
#pragma unroll
        for (int mt = 0; mt < 4; mt++) {
            int row = mt * 16 + c;
#pragma unroll
            for (int kh = 0; kh < 2; kh++) {
                int col = (kh * 64 + q * 16) ^ ((row & 7) << 4);
                af[mt][kh] = *(const bf16x8*)((const char*)&As[cur][0] + row * 128 + col);
            }
        }
#pragma unroll
        for (int nt = 0; nt < 4; nt++) {
            int row = w * 64 + nt * 16 + c;
#pragma unroll
            for (int kh = 0; kh < 2; kh++) {
                int col = (kh * 64 + q * 16) ^ ((row & 7) << 4);
                bf[nt][kh] = *(const bf16x8*)((const char*)&Bs[cur][0] + row * 128 + col);
            }
        }
#pragma unroll
        for (int mt = 0; mt < 4; mt++)
#pragma unroll
            for (int nt = 0; nt < 4; nt++) {
                acc[mt][nt] = __builtin_amdgcn_mfma_f32_16x16x32_bf16(
                    af[mt][0], bf[nt][0], acc[mt][nt], 0, 0, 0);
                acc[mt][nt] = __builtin_amdgcn_mfma_f32_16x16x32_bf16(
                    af[mt][1], bf[nt][1], acc[mt][nt], 0, 0, 0);
            }
        cur ^= 1;
    }

    float* dst = aggp + (size_t)ksp * (NN * NB * HH);
#pragma unroll
    for (int mt = 0; mt < 4; mt++)
#pragma unroll
        for (int nt = 0; nt < 4; nt++)
#pragma unroll
            for (int r = 0; r < 4; r++) {
                int x = m0 + mt * 16 + 4 * q + r;
                int n = w * 64 + nt * 16 + c;
                dst[(size_t)x * 1024 + b * 256 + n] = acc[mt][nt][r];
            }
}

// ---------------- k35: reduce 2 partials + normalize -> bf16 ----------------
__global__ void k35_norm(const float* __restrict__ aggp, const float* __restrict__ denom,
                         short* __restrict__ aggn) {
    int x = blockIdx.x, tid = threadIdx.x;
    int b = tid >> 6;
    int h4 = (tid & 63) * 4;
    size_t base = ((size_t)x * 4 + b) * 256 + h4;
    float4 s = {0.f, 0.f, 0.f, 0.f};
#pragma unroll
    for (int sp = 0; sp < KS; sp++) {
        float4 v = *(const float4*)(aggp + (size_t)sp * (NN * 4 * 256) + base);
        s.x += v.x; s.y += v.y; s.z += v.z; s.w += v.w;
    }
    float r = 1.f / fmaxf(denom[x * 4 + b], 1e-12f);
    short4 o = make_short4(f2bf(s.x * r), f2bf(s.y * r), f2bf(s.z * r), f2bf(s.w * r));
    *(short4*)(aggn + base) = o;
}

// ---------------- k4: fc_v + elu + residual + kl ----------------
__global__ __launch_bounds__(256) void k4_out(const short* __restrict__ aggn,
                                              const short* __restrict__ WvT,
                                              const float* __restrict__ bv,
                                              const float* __restrict__ h,
                                              const float* __restrict__ klsum,
                                              float* __restrict__ out) {
    int bx = blockIdx.x;
    int mt = bx >> 2, nb = bx & 3;
    int m0 = mt * 64, n0 = nb * 64;
    int tid = threadIdx.x, w = tid >> 6, lane = tid & 63, q = lane >> 4, c = lane & 15;
    int mrow = m0 + w * 16;
    f32x4 acc[4] = {{0, 0, 0, 0}, {0, 0, 0, 0}, {0, 0, 0, 0}, {0, 0, 0, 0}};
    for (int k0 = 0; k0 < 1024; k0 += 32) {
        bf16x8 af = *(const bf16x8*)(aggn + (mrow + c) * 1024 + k0 + q * 8);
#pragma unroll
        for (int nt = 0; nt < 4; nt++) {
            bf16x8 bf = *(const bf16x8*)(WvT + (n0 + nt * 16 + c) * 1024 + k0 + q * 8);
            acc[nt] = __builtin_amdgcn_mfma_f32_16x16x32_bf16(af, bf, acc[nt], 0, 0, 0);
        }
    }
#pragma unroll
    for (int nt = 0; nt < 4; nt++) {
        int col = n0 + nt * 16 + c;
        float bias = bv[col];
#pragma unroll
        for (int r = 0; r < 4; r++) {
            int row = mrow + 4 * q + r;
            float v = acc[nt][r] + bias;
            v = (v > 0.f) ? v : (__expf(v) - 1.f);  // elu
            out[row * 256 + col] = v + h[row * 256 + col];
        }
    }
    if (bx == 0 && tid == 0) out[786432] = klsum[0] * (1.0f / 9437184.0f);
}

extern "C" void kernel_launch(void* const* d_in, const int* in_sizes, int n_in,
                              void* d_out, int out_size, void* d_ws, size_t ws_size,
                              hipStream_t stream) {
    const float* h = (const float*)d_in[0];
    const float* gamma = (const float*)d_in[1];
    const float* beta = (const float*)d_in[2];
    const float* Wk = (const float*)d_in[3];
    const float* bk = (const float*)d_in[4];
    const float* Wmu = (const float*)d_in[5];
    const float* bmu = (const float*)d_in[6];
    const float* Wls = (const float*)d_in[7];
    const float* bls = (const float*)d_in[8];
    const float* Wv = (const float*)d_in[9];
    const float* bv = (const float*)d_in[10];
    const float* diff = (const float*)d_in[11];
    const float* eps = (const float*)d_in[12];
    float* out = (float*)d_out;

    char* p = (char*)d_ws;
    short* a = (short*)p;      p += (size_t)75497472;        // a[b][x][z] bf16, 75.5 MB
    float* aggp = (float*)p;   p += (size_t)KS * 12582912;   // 25.2 MB partial slices
    float* denom = (float*)p;  p += 49152;                   // + klsum contiguous
    float* klsum = (float*)p;  p += 4096;
    short* hn = (short*)p;     p += 1572864;
    short* hnT = (short*)p;    p += 1572864;
    short* kml = (short*)p;    p += 4718592;                 // fragment-packed
    short* WTcat = (short*)p;  p += 393216;
    float* biasc = (float*)p;  p += 4096;
    short* WvT = (short*)p;    p += 524288;
    short* aggn = (short*)p;                                 // 6291456; total ~116 MB

    k0_prep<<<165, 256, 0, stream>>>(Wk, Wmu, Wls, bk, bmu, bls, Wv, WTcat, biasc, WvT,
                                     denom);
    k1_ln<<<3072, 256, 0, stream>>>(h, gamma, beta, hn);
    k1b_tr<<<192, 256, 0, stream>>>(hn, hnT);
    k2_proj<<<576, 256, 0, stream>>>(hn, WTcat, biasc, kml);
    k3a_elem<<<192 * NCH, 256, 0, stream>>>(kml, eps, diff, a, denom, klsum);
    k3b_agg<<<48 * NB * KS, 256, 0, stream>>>(a, hnT, aggp);
    k35_norm<<<3072, 256, 0, stream>>>(aggp, denom, aggn);
    k4_out<<<192, 256, 0, stream>>>(aggn, WvT, bv, h, klsum, out);
}

// Round 3
// 433.910 us; speedup vs baseline: 1.0850x; 1.0080x over previous
//
#include <hip/hip_runtime.h>
#include <hip/hip_bf16.h>

// BronxLayer fused implementation for MI355X (gfx950).  Round 8 (= round 7
// resubmitted: round-7 bench died to container-infra failure, no counters).
// r6: 437us; k3a 165us latency-bound (VALUBusy 30%, MfmaUtil 2.3%, HBM 19%):
//   - 2/3 of per-wave loads were mu/ls kml fragments re-read by all 192
//     x-blocks (590 MB L2 traffic, serialized at ~250cy latency)
//   - short4 stores wrote 32B per 64B line -> WRITE_SIZE 142 MB vs 75.5 real
//   - old k3b: 24 barrier'd K-steps at 1.5 blocks/CU (imbalanced 384 grid)
// Round-7/8 changes:
//  - k3a: block = 64x * 64z; 4 waves share one z-stripe -> mu/ls fragments
//    staged ONCE per block into LDS via global_load_lds (16 KB/t-step,
//    double-buffered, 1 barrier per t-step, 4 per block).  Per-wave global
//    loads per t-step: 24 -> 12.
//  - `a` stored TILE-PACKED: 16x16 (x,z) tile = 512 contiguous bytes at
//    c*16+4q+r -> wave stores 512B coalesced (writes 142->78 MB) and k3b
//    reads A-fragments as single coalesced bf16x8 loads.
//  - k3b: barrier-free direct-load GEMM, 768 blocks (3/CU even), block =
//    64m x 64n, waves split K 2-way x n 2-way, one LDS pair-reduce, then
//    normalize + write bf16 aggn directly.  aggp (50 MB roundtrip) + k35
//    DELETED.  Workspace ~91 MB.

#define NN 3072
#define HH 256
#define NB 4
#define HD 64
constexpr int KMLSZ = 192 * 2 * 64 * 8;  // shorts per (mat,head)

typedef __attribute__((ext_vector_type(8))) short bf16x8;
typedef __attribute__((ext_vector_type(4))) float f32x4;

static __device__ inline short f2bf(float f) {
    __hip_bfloat16 h = __float2bfloat16(f);
    return __builtin_bit_cast(short, h);
}

typedef const __attribute__((address_space(1))) unsigned int* gas_ptr;
typedef __attribute__((address_space(3))) unsigned int* las_ptr;
static __device__ inline void gload_lds16(const void* g, void* l) {
    __builtin_amdgcn_global_load_lds((gas_ptr)g, (las_ptr)l, 16, 0, 0);
}

// ---------------- k0: weight prep + zero denom/klsum ----------------
__global__ void k0_prep(const float* __restrict__ Wk, const float* __restrict__ Wmu,
                        const float* __restrict__ Wls, const float* __restrict__ bk,
                        const float* __restrict__ bmu, const float* __restrict__ bls,
                        const float* __restrict__ Wv, short* __restrict__ WTcat,
                        float* __restrict__ biascat, short* __restrict__ WvT,
                        float* __restrict__ denom) {
    __shared__ float t[64][65];
    int bx = blockIdx.x;
    if (bx < 48) {
        int mat = bx >> 4;
        int by = (bx >> 2) & 3, bc = bx & 3;
        int y0 = by * 64, c0 = bc * 64;
        const float* W = (mat == 0) ? Wk : (mat == 1 ? Wmu : Wls);
        float scale = (mat == 0) ? 0.125f : 1.f;
        int r = threadIdx.x >> 4, c4 = (threadIdx.x & 15) * 4;
#pragma unroll
        for (int i = 0; i < 4; i++) {
            int yl = r + i * 16;
            float4 v = *(const float4*)(W + (y0 + yl) * 256 + c0 + c4);
            t[yl][c4] = v.x; t[yl][c4 + 1] = v.y; t[yl][c4 + 2] = v.z; t[yl][c4 + 3] = v.w;
        }
        __syncthreads();
#pragma unroll
        for (int i = 0; i < 4; i++) {
            int cl = r + i * 16;
            int corig = c0 + cl;
            int cp = mat * 256 + (corig & 3) * 64 + (corig >> 2);
            short4 v = make_short4(f2bf(t[c4][cl] * scale), f2bf(t[c4 + 1][cl] * scale),
                                   f2bf(t[c4 + 2][cl] * scale), f2bf(t[c4 + 3][cl] * scale));
            *(short4*)(WTcat + cp * 256 + y0 + c4) = v;
        }
        return;
    }
    if (bx < 112) {
        int b = bx - 48;
        int bk2 = b >> 2, bn = b & 3;
        int k0 = bk2 * 64, n0 = bn * 64;
        int r = threadIdx.x >> 4, c4 = (threadIdx.x & 15) * 4;
#pragma unroll
        for (int i = 0; i < 4; i++) {
            int kk = r + i * 16;
            float4 v = *(const float4*)(Wv + (k0 + kk) * 256 + n0 + c4);
            t[kk][c4] = v.x; t[kk][c4 + 1] = v.y; t[kk][c4 + 2] = v.z; t[kk][c4 + 3] = v.w;
        }
        __syncthreads();
#pragma unroll
        for (int i = 0; i < 4; i++) {
            int nn = r + i * 16;
            short4 v = make_short4(f2bf(t[c4][nn]), f2bf(t[c4 + 1][nn]),
                                   f2bf(t[c4 + 2][nn]), f2bf(t[c4 + 3][nn]));
            *(short4*)(WvT + (n0 + nn) * 1024 + k0 + c4) = v;
        }
        return;
    }
    if (bx == 112) {
        int cc = threadIdx.x;
        int corig = (cc & 63) * 4 + (cc >> 6);
        biascat[cc] = bk[corig] * 0.125f;
        biascat[256 + cc] = bmu[corig];
        biascat[512 + cc] = bls[corig];
        return;
    }
    int i = (bx - 113) * 256 + threadIdx.x;
    if (i < 13312) denom[i] = 0.f;   // denom[12288] then klsum[1024], contiguous
}

// ---------------- k1: LayerNorm ----------------
__global__ void k1_ln(const float* __restrict__ h, const float* __restrict__ gamma,
                      const float* __restrict__ beta, short* __restrict__ hn) {
    int row = blockIdx.x, tid = threadIdx.x;
    float v = h[row * 256 + tid];
    float s = v, s2 = v * v;
    for (int off = 32; off; off >>= 1) {
        s += __shfl_xor(s, off);
        s2 += __shfl_xor(s2, off);
    }
    __shared__ float red[8];
    int w = tid >> 6, lane = tid & 63;
    if (!lane) { red[w] = s; red[4 + w] = s2; }
    __syncthreads();
    s = red[0] + red[1] + red[2] + red[3];
    s2 = red[4] + red[5] + red[6] + red[7];
    float mean = s * (1.f / 256.f);
    float var = s2 * (1.f / 256.f) - mean * mean;
    float rs = rsqrtf(var + 1e-5f);
    hn[row * 256 + tid] = f2bf((v - mean) * rs * gamma[tid] + beta[tid]);
}

// ---------------- k1b: transpose hn -> hnT (LDS-tiled) ----------------
__global__ void k1b_tr(const short* __restrict__ hn, short* __restrict__ hnT) {
    __shared__ short t[64][68];
    int bn = blockIdx.x >> 2, bh = blockIdx.x & 3;
    int n0 = bn * 64, h0 = bh * 64;
    int r = threadIdx.x >> 4, c4 = (threadIdx.x & 15) * 4;
#pragma unroll
    for (int i = 0; i < 4; i++) {
        int nn = r + i * 16;
        *(short4*)&t[nn][c4] = *(const short4*)(hn + (n0 + nn) * 256 + h0 + c4);
    }
    __syncthreads();
#pragma unroll
    for (int i = 0; i < 4; i++) {
        int hh = r + i * 16;
        short4 v = make_short4(t[c4][hh], t[c4 + 1][hh], t[c4 + 2][hh], t[c4 + 3][hh]);
        *(short4*)(hnT + (h0 + hh) * NN + n0 + c4) = v;
    }
}

// ---------------- k2: projections (bf16 MFMA), fragment-packed output -----------
// kml packed per (mat,head): idx = ((zt*2 + khalf)*64 + lane)*8 + j
//   element: node z = zt*16 + (lane&15), k = khalf*32 + (lane>>4)*8 + j
__global__ __launch_bounds__(256) void k2_proj(const short* __restrict__ hn,
                                               const short* __restrict__ WTcat,
                                               const float* __restrict__ biascat,
                                               short* __restrict__ kml) {
    int bx = blockIdx.x;
    int mt = bx / 12, nb = bx % 12;
    int m0 = mt * 64, n0 = nb * 64;
    int tid = threadIdx.x, w = tid >> 6, lane = tid & 63, q = lane >> 4, c = lane & 15;
    int mrow = m0 + w * 16;
    f32x4 acc[4] = {{0, 0, 0, 0}, {0, 0, 0, 0}, {0, 0, 0, 0}, {0, 0, 0, 0}};
    for (int k0 = 0; k0 < 256; k0 += 32) {
        bf16x8 af = *(const bf16x8*)(hn + (mrow + c) * 256 + k0 + q * 8);
#pragma unroll
        for (int nt = 0; nt < 4; nt++) {
            bf16x8 bf = *(const bf16x8*)(WTcat + (n0 + nt * 16 + c) * 256 + k0 + q * 8);
            acc[nt] = __builtin_amdgcn_mfma_f32_16x16x32_bf16(af, bf, acc[nt], 0, 0, 0);
        }
    }
#pragma unroll
    for (int nt = 0; nt < 4; nt++) {
        int cp = n0 + nt * 16 + c;
        float bias = biascat[cp];
        int mat = cp >> 8, b = (cp >> 6) & 3, y = cp & 63;
        short* dst = kml + (size_t)(mat * 4 + b) * KMLSZ;
        int kh2 = y >> 5, lq = (y >> 3) & 3, j = y & 7;
        int zt = mt * 4 + w;  // m>>4
#pragma unroll
        for (int r = 0; r < 4; r++) {
            int ml = 4 * q + r;  // m&15
            dst[(((zt * 2 + kh2) * 64) + lq * 16 + ml) * 8 + j] = f2bf(acc[nt][r] + bias);
        }
    }
}

// ---------------- k3a: elementwise core ----------------
// Block: 64 x (wave w -> x-tile xb*4+w) x 64 z (shared by all waves).
// mu/ls fragments for the current 16-z tile staged once per block into LDS
// (global_load_lds, double-buffered, 1 barrier/t-step).  eps/diff -> regs.
// Output a tile-packed: tile (b, xt, zt2) = 256 shorts at [c*16 + 4q + r].
__global__ __launch_bounds__(256) void k3a_elem(
    const short* __restrict__ kml, const float* __restrict__ eps,
    const float* __restrict__ diff, short* __restrict__ apk,
    float* __restrict__ denom, float* __restrict__ klsum) {
    __shared__ short frag[2][16][512];   // [buf][f=mat*8+b*2+kh][lane*8]
    __shared__ float klred[4];
    const int tid = threadIdx.x;
    const int w = tid >> 6, lane = tid & 63, q = lane >> 4, c = lane & 15;
    const int xb = blockIdx.x % 48;
    const int zc = blockIdx.x / 48;
    const int xt = xb * 4 + w;     // this wave's x-tile, 0..191
    const int x0 = xt * 16;

    // stage mu/ls fragments for 16-z tile zt2; wave w stages f = w*4..w*4+3
    auto stage = [&](int buf, int zt2) {
#pragma unroll
        for (int i = 0; i < 4; i++) {
            int f = w * 4 + i;
            int mat = f >> 3, bh = (f >> 1) & 3, kh = f & 1;
            const short* plane = kml + (size_t)((mat + 1) * 4 + bh) * KMLSZ;
            gload_lds16(plane + ((zt2 * 2 + kh) * 64 + lane) * 8, &frag[buf][f][0]);
        }
    };

    // kh fragments (B-operand of S^T), hoisted: one per (head, k-half)
    bf16x8 qf[NB][2];
#pragma unroll
    for (int b = 0; b < NB; b++)
#pragma unroll
        for (int kh = 0; kh < 2; kh++)
            qf[b][kh] = *(const bf16x8*)(kml + (size_t)b * KMLSZ +
                                         ((xt * 2 + kh) * 64 + lane) * 8);

    stage(0, zc * 4);

    float den_acc[NB] = {0.f, 0.f, 0.f, 0.f};
    float kl_acc = 0.f;
    const size_t xrow = (size_t)(x0 + c) * NN;

    for (int t = 0; t < 4; t++) {
        const int buf = t & 1;
        const int zt2 = zc * 4 + t;
        const int z16 = zt2 * 16;
        __syncthreads();                     // frag[buf] staged (vmcnt drained)
        if (t < 3) stage(buf ^ 1, zt2 + 1);  // prefetch next tile's fragments
        // eps/diff for this t (used late, after MFMA -> natural overlap)
        f32x4 e4[4];
        float dif[4];
#pragma unroll
        for (int r = 0; r < 4; r++) {
            e4[r] = *(const f32x4*)(eps + (xrow + (size_t)(z16 + 4 * q + r)) * 4);
            dif[r] = diff[xrow + z16 + 4 * q + r];
        }
#pragma unroll
        for (int b = 0; b < NB; b++) {
            bf16x8 a0 = *(const bf16x8*)&frag[buf][b * 2 + 0][lane * 8];
            bf16x8 a1 = *(const bf16x8*)&frag[buf][b * 2 + 1][lane * 8];
            bf16x8 l0 = *(const bf16x8*)&frag[buf][8 + b * 2 + 0][lane * 8];
            bf16x8 l1 = *(const bf16x8*)&frag[buf][8 + b * 2 + 1][lane * 8];
            f32x4 smu = {0.f, 0.f, 0.f, 0.f};
            smu = __builtin_amdgcn_mfma_f32_16x16x32_bf16(a0, qf[b][0], smu, 0, 0, 0);
            smu = __builtin_amdgcn_mfma_f32_16x16x32_bf16(a1, qf[b][1], smu, 0, 0, 0);
            f32x4 sls = {0.f, 0.f, 0.f, 0.f};
            sls = __builtin_amdgcn_mfma_f32_16x16x32_bf16(l0, qf[b][0], sls, 0, 0, 0);
            sls = __builtin_amdgcn_mfma_f32_16x16x32_bf16(l1, qf[b][1], sls, 0, 0, 0);
            short pk[4];
#pragma unroll
            for (int r = 0; r < 4; r++) {
                float mu = smu[r];
                float ls = sls[r];
                float e = e4[r][b];
                float d = dif[r];
                float ex = __expf(-fabsf(ls));
                float sg = fmaxf(ls, 0.f) + __logf(1.f + ex);
                float kle = -__logf(sg) + 0.5f * (sg * sg + mu * mu) - 0.5f;
                float sgn = (d > 0.f) ? 1.f : ((d < 0.f) ? -1.f : 0.f);
                kl_acc += sgn * kle;
                float av = __expf(mu + sg * e) * d;
                den_acc[b] += fabsf(av);
                pk[r] = f2bf(av);
            }
            // tile-packed store: wave writes 512B contiguous per (t,b)
            *(short4*)(apk + (((size_t)b * 192 + xt) * 192 + zt2) * 256 + c * 16 + q * 4) =
                make_short4(pk[0], pk[1], pk[2], pk[3]);
        }
    }
    // denominator: lane's elements all at x = x0 + c; reduce across quads
#pragma unroll
    for (int b = 0; b < NB; b++) {
        float d = den_acc[b];
        d += __shfl_down(d, 32);
        d += __shfl_down(d, 16);
        if (q == 0) atomicAdd(&denom[(x0 + c) * NB + b], d);
    }
    for (int off = 32; off; off >>= 1) kl_acc += __shfl_xor(kl_acc, off);
    if (lane == 0) klred[w] = kl_acc;
    __syncthreads();
    if (tid == 0) atomicAdd(klsum, klred[0] + klred[1] + klred[2] + klred[3]);
}

// ---------------- k3b: aggregation GEMM + normalize -> bf16 ----------------
// aggn[x, b*256+h] = (sum_z a_b[x,z] hnT[h,z]) / denom[x,b].  Block = 64m x
// 64n per head; waves split K 2-way (kw) x n 2-way (nw).  Barrier-free main
// loop (direct global loads: A tile-packed coalesced, B = hnT k2-style);
// one LDS pair-reduce over kw at the end, then normalize and emit bf16.
__global__ __launch_bounds__(256) void k3b_agg(
    const short* __restrict__ apk, const short* __restrict__ hnT,
    const float* __restrict__ denom, short* __restrict__ aggn) {
    __shared__ float red[2][64 * 33];   // [nw][m*33 + nl], pad 33 vs bank conflicts
    const int tid = threadIdx.x;
    const int w = tid >> 6, lane = tid & 63, q = lane >> 4, c = lane & 15;
    const int kw = w >> 1, nw = w & 1;
    const int bid = blockIdx.x;
    const int b = bid & 3;
    const int nb = (bid >> 2) & 3;
    const int mb = bid >> 4;            // 0..47
    const int m0 = mb * 64;
    const int n0 = nb * 64 + nw * 32;
    const int q2 = q >> 1, q1 = q & 1;

    f32x4 acc[4][2];
#pragma unroll
    for (int i = 0; i < 4; i++)
#pragma unroll
        for (int j = 0; j < 2; j++) acc[i][j] = (f32x4){0.f, 0.f, 0.f, 0.f};

    const size_t abase = ((size_t)b * 192 + mb * 4) * 192 * 256;
    for (int ks = 0; ks < 48; ks++) {
        const int kglob = kw * 1536 + ks * 32;
        const int T2 = kw * 96 + ks * 2;   // 16-z tile index base
        bf16x8 af[4], bf[2];
#pragma unroll
        for (int mt = 0; mt < 4; mt++)
            af[mt] = *(const bf16x8*)(apk + abase +
                                      (size_t)(mt * 192 + T2 + q2) * 256 + c * 16 + q1 * 8);
#pragma unroll
        for (int nt = 0; nt < 2; nt++)
            bf[nt] = *(const bf16x8*)(hnT + (size_t)(n0 + nt * 16 + c) * NN + kglob + q * 8);
#pragma unroll
        for (int mt = 0; mt < 4; mt++)
#pragma unroll
            for (int nt = 0; nt < 2; nt++)
                acc[mt][nt] = __builtin_amdgcn_mfma_f32_16x16x32_bf16(
                    af[mt], bf[nt], acc[mt][nt], 0, 0, 0);
    }

    if (kw == 1) {
#pragma unroll
        for (int mt = 0; mt < 4; mt++)
#pragma unroll
            for (int nt = 0; nt < 2; nt++)
#pragma unroll
                for (int r = 0; r < 4; r++)
                    red[nw][(mt * 16 + 4 * q + r) * 33 + nt * 16 + c] = acc[mt][nt][r];
    }
    __syncthreads();
    if (kw == 0) {
#pragma unroll
        for (int mt = 0; mt < 4; mt++)
#pragma unroll
            for (int r = 0; r < 4; r++) {
                int x = m0 + mt * 16 + 4 * q + r;
                float rcp = 1.f / fmaxf(denom[x * 4 + b], 1e-12f);
#pragma unroll
                for (int nt = 0; nt < 2; nt++) {
                    float s = acc[mt][nt][r] + red[nw][(mt * 16 + 4 * q + r) * 33 + nt * 16 + c];
                    aggn[(size_t)x * 1024 + b * 256 + n0 + nt * 16 + c] = f2bf(s * rcp);
                }
            }
    }
}

// ---------------- k4: fc_v + elu + residual + kl ----------------
__global__ __launch_bounds__(256) void k4_out(const short* __restrict__ aggn,
                                              const short* __restrict__ WvT,
                                              const float* __restrict__ bv,
                                              const float* __restrict__ h,
                                              const float* __restrict__ klsum,
                                              float* __restrict__ out) {
    int bx = blockIdx.x;
    int mt = bx >> 2, nb = bx & 3;
    int m0 = mt * 64, n0 = nb * 64;
    int tid = threadIdx.x, w = tid >> 6, lane = tid & 63, q = lane >> 4, c = lane & 15;
    int mrow = m0 + w * 16;
    f32x4 acc[4] = {{0, 0, 0, 0}, {0, 0, 0, 0}, {0, 0, 0, 0}, {0, 0, 0, 0}};
    for (int k0 = 0; k0 < 1024; k0 += 32) {
        bf16x8 af = *(const bf16x8*)(aggn + (mrow + c) * 1024 + k0 + q * 8);
#pragma unroll
        for (int nt = 0; nt < 4; nt++) {
            bf16x8 bf = *(const bf16x8*)(WvT + (n0 + nt * 16 + c) * 1024 + k0 + q * 8);
            acc[nt] = __builtin_amdgcn_mfma_f32_16x16x32_bf16(af, bf, acc[nt], 0, 0, 0);
        }
    }
#pragma unroll
    for (int nt = 0; nt < 4; nt++) {
        int col = n0 + nt * 16 + c;
        float bias = bv[col];
#pragma unroll
        for (int r = 0; r < 4; r++) {
            int row = mrow + 4 * q + r;
            float v = acc[nt][r] + bias;
            v = (v > 0.f) ? v : (__expf(v) - 1.f);  // elu
            out[row * 256 + col] = v + h[row * 256 + col];
        }
    }
    if (bx == 0 && tid == 0) out[786432] = klsum[0] * (1.0f / 9437184.0f);
}

extern "C" void kernel_launch(void* const* d_in, const int* in_sizes, int n_in,
                              void* d_out, int out_size, void* d_ws, size_t ws_size,
                              hipStream_t stream) {
    const float* h = (const float*)d_in[0];
    const float* gamma = (const float*)d_in[1];
    const float* beta = (const float*)d_in[2];
    const float* Wk = (const float*)d_in[3];
    const float* bk = (const float*)d_in[4];
    const float* Wmu = (const float*)d_in[5];
    const float* bmu = (const float*)d_in[6];
    const float* Wls = (const float*)d_in[7];
    const float* bls = (const float*)d_in[8];
    const float* Wv = (const float*)d_in[9];
    const float* bv = (const float*)d_in[10];
    const float* diff = (const float*)d_in[11];
    const float* eps = (const float*)d_in[12];
    float* out = (float*)d_out;

    char* p = (char*)d_ws;
    short* apk = (short*)p;    p += (size_t)75497472;  // a tile-packed, 75.5 MB
    float* denom = (float*)p;  p += 49152;             // + klsum contiguous
    float* klsum = (float*)p;  p += 4096;
    short* hn = (short*)p;     p += 1572864;
    short* hnT = (short*)p;    p += 1572864;
    short* kml = (short*)p;    p += 4718592;           // fragment-packed
    short* WTcat = (short*)p;  p += 393216;
    float* biasc = (float*)p;  p += 4096;
    short* WvT = (short*)p;                            // 524288
    // aggn reuses the front of apk: k3b consumes apk and writes aggn, but
    // reads of a tile finish before that tile's x-row output is written?
    // NOT guaranteed -> keep aggn separate (space is ample).
    p += 524288;
    short* aggn = (short*)p;                           // 6291456; total ~90.6 MB

    k0_prep<<<165, 256, 0, stream>>>(Wk, Wmu, Wls, bk, bmu, bls, Wv, WTcat, biasc, WvT,
                                     denom);
    k1_ln<<<3072, 256, 0, stream>>>(h, gamma, beta, hn);
    k1b_tr<<<192, 256, 0, stream>>>(hn, hnT);
    k2_proj<<<576, 256, 0, stream>>>(hn, WTcat, biasc, kml);
    k3a_elem<<<48 * 48, 256, 0, stream>>>(kml, eps, diff, apk, denom, klsum);
    k3b_agg<<<48 * 4 * 4, 256, 0, stream>>>(apk, hnT, denom, aggn);
    k4_out<<<192, 256, 0, stream>>>(aggn, WvT, bv, h, klsum, out);
}